// Round 2
// baseline (118.137 us; speedup 1.0000x reference)
//
#include <hip/hip_runtime.h>
#include <math.h>

#define LN_EPS 1e-5f
#define ROWS_PER_BLOCK 64   // 16 rows per wave, 8 pairs

typedef int   vint4   __attribute__((ext_vector_type(4)));
typedef float vfloat2 __attribute__((ext_vector_type(2)));
typedef float vfloat4 __attribute__((ext_vector_type(4)));

// ---------- DPP wave64 sum: 6 fused v_add_f32_dpp + 1 readlane ----------
template<int CTRL>
__device__ __forceinline__ float dppadd(float x) {
    int y = __builtin_amdgcn_update_dpp(0, __float_as_int(x), CTRL, 0xf, 0xf, true);
    return x + __int_as_float(y);
}
__device__ __forceinline__ float wave_sum(float x) {
    x = dppadd<0xB1>(x);
    x = dppadd<0x4E>(x);
    x = dppadd<0x141>(x);
    x = dppadd<0x140>(x);
    x = dppadd<0x142>(x);
    x = dppadd<0x143>(x);
    return __int_as_float(__builtin_amdgcn_readlane(__float_as_int(x), 63));
}

// tanh-form GELU via v_exp/v_rcp; max abs err ~3e-3 (threshold 0.63)
__device__ __forceinline__ float gelu_f(float x) {
    float t = x * fmaf(x * x, 0.044715f, 1.0f) * 1.5957691216057308f;
    float e = __expf(-t);
    return x * __builtin_amdgcn_rcpf(1.0f + e);
}

// Pack xy of both batches: xyp[n] = {x(b0,n), y(b0,n), x(b1,n), y(b1,n)}
__global__ __launch_bounds__(256) void pack_kernel(
    const float* __restrict__ stat, float4* __restrict__ xyp, int N)
{
    int n = blockIdx.x * blockDim.x + threadIdx.x;
    if (n >= N) return;
    float2 a = *reinterpret_cast<const float2*>(stat + (size_t)n * 16);
    float2 b = *reinterpret_cast<const float2*>(stat + (size_t)(n + N) * 16);
    xyp[n] = make_float4(a.x, a.y, b.x, b.y);
}

// Rows come from LDS (wave-uniform broadcast ds_read_b128, conflict-free,
// counted lgkmcnt -> compiler pipelines finely; no SMEM lgkmcnt(0) drain).
// Layout B: lane owns cols (2*lane, 2*lane+1) -> one dwordx2 NT store per row.
__device__ __forceinline__ void compute_pair_lds(
    float* __restrict__ out, const float* sA_base, int rloc, int r, int n_rows,
    const vfloat2 (&w)[16], vfloat2 bb, vfloat2 gg, vfloat2 ee, int lane)
{
    if (r >= n_rows) return;
    const bool two = (r + 1 < n_rows);
    const float* sA = sA_base + rloc * 16;
    const float* sB = sA + (two ? 16 : 0);

    float4 a0 = *reinterpret_cast<const float4*>(sA + 0);
    float4 a1 = *reinterpret_cast<const float4*>(sA + 4);
    float4 a2 = *reinterpret_cast<const float4*>(sA + 8);
    float4 a3 = *reinterpret_cast<const float4*>(sA + 12);
    float4 c0 = *reinterpret_cast<const float4*>(sB + 0);
    float4 c1 = *reinterpret_cast<const float4*>(sB + 4);
    float4 c2 = *reinterpret_cast<const float4*>(sB + 8);
    float4 c3 = *reinterpret_cast<const float4*>(sB + 12);

    float pA[16], pB[16];
    pA[0]=a0.x; pA[1]=a0.y; pA[2]=a0.z; pA[3]=a0.w;
    pA[4]=a1.x; pA[5]=a1.y; pA[6]=a1.z; pA[7]=a1.w;
    pA[8]=a2.x; pA[9]=a2.y; pA[10]=a2.z; pA[11]=a2.w;
    pA[12]=a3.x; pA[13]=a3.y; pA[14]=a3.z; pA[15]=a3.w;
    pB[0]=c0.x; pB[1]=c0.y; pB[2]=c0.z; pB[3]=c0.w;
    pB[4]=c1.x; pB[5]=c1.y; pB[6]=c1.z; pB[7]=c1.w;
    pB[8]=c2.x; pB[9]=c2.y; pB[10]=c2.z; pB[11]=c2.w;
    pB[12]=c3.x; pB[13]=c3.y; pB[14]=c3.z; pB[15]=c3.w;

    float xA0 = bb.x, xA1 = bb.y, xB0 = bb.x, xB1 = bb.y;
#pragma unroll
    for (int c = 0; c < 16; ++c) {
        xA0 = fmaf(pA[c], w[c].x, xA0);
        xA1 = fmaf(pA[c], w[c].y, xA1);
        xB0 = fmaf(pB[c], w[c].x, xB0);
        xB1 = fmaf(pB[c], w[c].y, xB1);
    }
    xA0 = gelu_f(xA0); xA1 = gelu_f(xA1);
    xB0 = gelu_f(xB0); xB1 = gelu_f(xB1);

    const float sumA = wave_sum(xA0 + xA1);
    const float sqA  = wave_sum(xA0 * xA0 + xA1 * xA1);
    const float sumB = wave_sum(xB0 + xB1);
    const float sqB  = wave_sum(xB0 * xB0 + xB1 * xB1);

    const float muA = sumA * (1.0f / 128.0f);
    const float invA = rsqrtf(sqA * (1.0f / 128.0f) - muA * muA + LN_EPS);
    const float muB = sumB * (1.0f / 128.0f);
    const float invB = rsqrtf(sqB * (1.0f / 128.0f) - muB * muB + LN_EPS);

    vfloat2 oA;
    oA.x = (xA0 - muA) * invA * gg.x + ee.x;
    oA.y = (xA1 - muA) * invA * gg.y + ee.y;
    __builtin_nontemporal_store(oA,
        reinterpret_cast<vfloat2*>(out + (size_t)r * 128 + 2 * lane));
    if (two) {
        vfloat2 oB;
        oB.x = (xB0 - muB) * invB * gg.x + ee.x;
        oB.y = (xB1 - muB) * invB * gg.y + ee.y;
        __builtin_nontemporal_store(oB,
            reinterpret_cast<vfloat2*>(out + (size_t)(r + 1) * 128 + 2 * lane));
    }
}

// LDS-staged fusion. 64 rows/block => blocks_h == blocks_d (1563 each at
// this shape): every block carries identical row+det work, no imbalance.
//   idx NT loads -> coalesced stage (float4 + ds_write_b128) -> weights
//   -> barrier -> pairs 0..3 -> det (gather+math+store, idx long since
//   landed) -> pairs 4..7
__global__ __launch_bounds__(256) void fused4_kernel(
    const float* __restrict__ stat, const float* __restrict__ fc_w,
    const float* __restrict__ fc_b, const float* __restrict__ ln_g,
    const float* __restrict__ ln_b, float* __restrict__ out,
    const float4* __restrict__ xyp, const int* __restrict__ ei,
    float* __restrict__ det, int n_rows, int E, int E_vec)
{
    __shared__ float srows[ROWS_PER_BLOCK * 16];

    const int tidL = (int)threadIdx.x;
    const int tid  = blockIdx.x * 256 + tidL;
    const int lane = tidL & 63;
    const int wave = tidL >> 6;                  // 0..3
    const int R0   = blockIdx.x * ROWS_PER_BLOCK;

    // det stage 0: index loads (HBM ~900cyc; consumed after 4 pairs)
    const int i4 = tid * 4;
    const bool has_det = (i4 + 3 < E_vec);
    vint4 s = {0, 0, 0, 0}, d = {0, 0, 0, 0};
    if (has_det) {
        s = __builtin_nontemporal_load(reinterpret_cast<const vint4*>(ei + i4));
        d = __builtin_nontemporal_load(reinterpret_cast<const vint4*>(ei + E + i4));
    }

    // stage: thread t loads quarter-row (16B), fully coalesced 4KB/block
    {
        int rq = R0 + (tidL >> 2);
        rq = rq < n_rows ? rq : (n_rows - 1);     // clamp, never OOB
        float4 v = *reinterpret_cast<const float4*>(
            stat + (size_t)rq * 16 + (tidL & 3) * 4);
        *reinterpret_cast<float4*>(&srows[tidL * 4]) = v;
    }

    vfloat2 w[16];
#pragma unroll
    for (int c = 0; c < 16; ++c)
        w[c] = *reinterpret_cast<const vfloat2*>(fc_w + c * 128 + 2 * lane);
    const vfloat2 bb = *reinterpret_cast<const vfloat2*>(fc_b + 2 * lane);
    const vfloat2 gg = *reinterpret_cast<const vfloat2*>(ln_g + 2 * lane);
    const vfloat2 ee = *reinterpret_cast<const vfloat2*>(ln_b + 2 * lane);

    __syncthreads();

    const int r0 = R0 + wave * 16;
    const float* sbase = &srows[wave * 16 * 16];

    compute_pair_lds(out, sbase, 0, r0 + 0,  n_rows, w, bb, gg, ee, lane);
    compute_pair_lds(out, sbase, 2, r0 + 2,  n_rows, w, bb, gg, ee, lane);
    compute_pair_lds(out, sbase, 4, r0 + 4,  n_rows, w, bb, gg, ee, lane);
    compute_pair_lds(out, sbase, 6, r0 + 6,  n_rows, w, bb, gg, ee, lane);

    // det: gathers (L2-resident xyp) + consume + dwordx4 NT stores, contiguous
    if (has_det) {
        float4 gs0 = xyp[s.x], gd0 = xyp[d.x];
        float4 gs1 = xyp[s.y], gd1 = xyp[d.y];
        float4 gs2 = xyp[s.z], gd2 = xyp[d.z];
        float4 gs3 = xyp[s.w], gd3 = xyp[d.w];
        float dx, dy;
        vfloat4 o0, o1;
        dx = gs0.x - gd0.x; dy = gs0.y - gd0.y; o0.x = -0.5f * (dx*dx + dy*dy);
        dx = gs1.x - gd1.x; dy = gs1.y - gd1.y; o0.y = -0.5f * (dx*dx + dy*dy);
        dx = gs2.x - gd2.x; dy = gs2.y - gd2.y; o0.z = -0.5f * (dx*dx + dy*dy);
        dx = gs3.x - gd3.x; dy = gs3.y - gd3.y; o0.w = -0.5f * (dx*dx + dy*dy);
        dx = gs0.z - gd0.z; dy = gs0.w - gd0.w; o1.x = -0.5f * (dx*dx + dy*dy);
        dx = gs1.z - gd1.z; dy = gs1.w - gd1.w; o1.y = -0.5f * (dx*dx + dy*dy);
        dx = gs2.z - gd2.z; dy = gs2.w - gd2.w; o1.z = -0.5f * (dx*dx + dy*dy);
        dx = gs3.z - gd3.z; dy = gs3.w - gd3.w; o1.w = -0.5f * (dx*dx + dy*dy);
        __builtin_nontemporal_store(o0, reinterpret_cast<vfloat4*>(det + i4));
        __builtin_nontemporal_store(o1, reinterpret_cast<vfloat4*>(det + E + i4));
    }

    compute_pair_lds(out, sbase, 8,  r0 + 8,  n_rows, w, bb, gg, ee, lane);
    compute_pair_lds(out, sbase, 10, r0 + 10, n_rows, w, bb, gg, ee, lane);
    compute_pair_lds(out, sbase, 12, r0 + 12, n_rows, w, bb, gg, ee, lane);
    compute_pair_lds(out, sbase, 14, r0 + 14, n_rows, w, bb, gg, ee, lane);
}

// det-only tail / ws-less fallback
__global__ __launch_bounds__(256) void det_kernel_direct(
    const float* __restrict__ stat, const int* __restrict__ ei,
    float* __restrict__ det, int E, int N, int i0)
{
    int i = i0 + (blockIdx.x * blockDim.x + threadIdx.x) * 2;
    if (i >= E) return;
    int2 s = *reinterpret_cast<const int2*>(ei + i);
    int2 d = *reinterpret_cast<const int2*>(ei + E + i);
#pragma unroll
    for (int b = 0; b < 2; ++b) {
        const float* base = stat + (size_t)b * N * 16;
        float2 ps0 = *reinterpret_cast<const float2*>(base + (size_t)s.x * 16);
        float2 pd0 = *reinterpret_cast<const float2*>(base + (size_t)d.x * 16);
        float2 ps1 = *reinterpret_cast<const float2*>(base + (size_t)s.y * 16);
        float2 pd1 = *reinterpret_cast<const float2*>(base + (size_t)d.y * 16);
        float dx0 = ps0.x - pd0.x, dy0 = ps0.y - pd0.y;
        float dx1 = ps1.x - pd1.x, dy1 = ps1.y - pd1.y;
        float2 v;
        v.x = -0.5f * (dx0 * dx0 + dy0 * dy0);
        v.y = -0.5f * (dx1 * dx1 + dy1 * dy1);
        *reinterpret_cast<float2*>(det + (size_t)b * E + i) = v;
    }
}

extern "C" void kernel_launch(void* const* d_in, const int* in_sizes, int n_in,
                              void* d_out, int out_size, void* d_ws, size_t ws_size,
                              hipStream_t stream) {
    const float* stat = (const float*)d_in[0];
    const int*   ei   = (const int*)d_in[1];
    const float* fc_w = (const float*)d_in[2];
    const float* fc_b = (const float*)d_in[3];
    const float* ln_g = (const float*)d_in[4];
    const float* ln_b = (const float*)d_in[5];
    float* out = (float*)d_out;

    const int n_rows = in_sizes[0] / 16;   // B*N = 100000
    const int E      = in_sizes[1] / 2;    // 1600000
    const int N      = n_rows / 2;         // B = 2

    float* H0  = out;
    float* det = out + (size_t)n_rows * 128;
    float* xyp = (float*)d_ws;
    const bool use_ws = (ws_size >= (size_t)N * 4 * sizeof(float));

    if (use_ws) {
        pack_kernel<<<(N + 255) / 256, 256, 0, stream>>>(stat, (float4*)xyp, N);
        // fused det path needs 16B alignment of ei+E / det+E: requires E%4==0
        const int E_vec = (E % 4 == 0) ? E : 0;
        const int blocks_h = (n_rows + ROWS_PER_BLOCK - 1) / ROWS_PER_BLOCK;
        const int blocks_d = (E_vec + 1023) / 1024;     // 1024 edges/block
        const int G = blocks_h > blocks_d ? blocks_h : blocks_d;
        fused4_kernel<<<G, 256, 0, stream>>>(stat, fc_w, fc_b, ln_g, ln_b, H0,
                                             (const float4*)xyp, ei, det,
                                             n_rows, E, E_vec);
        long long covered = (long long)G * 1024;
        if (covered > E_vec) covered = E_vec;
        if (covered < E) {
            const int rem_pairs = (int)((E - covered + 1) / 2);
            det_kernel_direct<<<(rem_pairs + 255) / 256, 256, 0, stream>>>(
                stat, ei, det, E, N, (int)covered);
        }
    } else {
        const int pairs = (E + 1) / 2;
        det_kernel_direct<<<(pairs + 255) / 256, 256, 0, stream>>>(stat, ei, det, E, N, 0);
        const int blocks_h = (n_rows + ROWS_PER_BLOCK - 1) / ROWS_PER_BLOCK;
        fused4_kernel<<<blocks_h, 256, 0, stream>>>(stat, fc_w, fc_b, ln_g, ln_b, H0,
                                                    (const float4*)xyp, ei, det,
                                                    n_rows, E, 0);
    }
}

// Round 3
// 117.953 us; speedup vs baseline: 1.0016x; 1.0016x over previous
//
#include <hip/hip_runtime.h>
#include <math.h>

#define LN_EPS 1e-5f
#define RPB 32    // rows per block   (2 row-waves x 16 rows)
#define EPB 512   // edges per block  (2 det-waves x 64 lanes x 4 edges)

typedef int   vint4   __attribute__((ext_vector_type(4)));
typedef float vfloat2 __attribute__((ext_vector_type(2)));
typedef float vfloat4 __attribute__((ext_vector_type(4)));

// ---------- DPP wave64 sum: 6 fused v_add_f32_dpp + 1 readlane ----------
template<int CTRL>
__device__ __forceinline__ float dppadd(float x) {
    int y = __builtin_amdgcn_update_dpp(0, __float_as_int(x), CTRL, 0xf, 0xf, true);
    return x + __int_as_float(y);
}
__device__ __forceinline__ float wave_sum(float x) {
    x = dppadd<0xB1>(x);
    x = dppadd<0x4E>(x);
    x = dppadd<0x141>(x);
    x = dppadd<0x140>(x);
    x = dppadd<0x142>(x);
    x = dppadd<0x143>(x);
    return __int_as_float(__builtin_amdgcn_readlane(__float_as_int(x), 63));
}

// tanh-form GELU via v_exp/v_rcp; max abs err ~3e-3 (threshold 0.63)
__device__ __forceinline__ float gelu_f(float x) {
    float t = x * fmaf(x * x, 0.044715f, 1.0f) * 1.5957691216057308f;
    float e = __expf(-t);
    return x * __builtin_amdgcn_rcpf(1.0f + e);
}

// Pack xy of both batches: xyp[n] = {x(b0,n), y(b0,n), x(b1,n), y(b1,n)}
__global__ __launch_bounds__(256) void pack_kernel(
    const float* __restrict__ stat, float4* __restrict__ xyp, int N)
{
    int n = blockIdx.x * blockDim.x + threadIdx.x;
    if (n >= N) return;
    float2 a = *reinterpret_cast<const float2*>(stat + (size_t)n * 16);
    float2 b = *reinterpret_cast<const float2*>(stat + (size_t)(n + N) * 16);
    xyp[n] = make_float4(a.x, a.y, b.x, b.y);
}

// Rows from LDS (wave-uniform broadcast ds_read_b128, conflict-free, counted
// lgkmcnt). Inline float4 consumption keeps the live set small.
// Layout B: lane owns cols (2*lane, 2*lane+1) -> one dwordx2 NT store per row.
__device__ __forceinline__ void compute_pair_lds(
    float* __restrict__ out, const float* sA, int r, int n_rows,
    const vfloat2 (&w)[16], vfloat2 bb, vfloat2 gg, vfloat2 ee, int lane)
{
    if (r >= n_rows) return;
    const bool two = (r + 1 < n_rows);
    const float4* rowA = reinterpret_cast<const float4*>(sA);
    const float4* rowB = reinterpret_cast<const float4*>(sA + (two ? 16 : 0));

    float xA0 = bb.x, xA1 = bb.y, xB0 = bb.x, xB1 = bb.y;
#pragma unroll
    for (int q = 0; q < 4; ++q) {
        float4 a = rowA[q];
        float4 b = rowB[q];
        xA0 = fmaf(a.x, w[4*q+0].x, xA0); xA1 = fmaf(a.x, w[4*q+0].y, xA1);
        xB0 = fmaf(b.x, w[4*q+0].x, xB0); xB1 = fmaf(b.x, w[4*q+0].y, xB1);
        xA0 = fmaf(a.y, w[4*q+1].x, xA0); xA1 = fmaf(a.y, w[4*q+1].y, xA1);
        xB0 = fmaf(b.y, w[4*q+1].x, xB0); xB1 = fmaf(b.y, w[4*q+1].y, xB1);
        xA0 = fmaf(a.z, w[4*q+2].x, xA0); xA1 = fmaf(a.z, w[4*q+2].y, xA1);
        xB0 = fmaf(b.z, w[4*q+2].x, xB0); xB1 = fmaf(b.z, w[4*q+2].y, xB1);
        xA0 = fmaf(a.w, w[4*q+3].x, xA0); xA1 = fmaf(a.w, w[4*q+3].y, xA1);
        xB0 = fmaf(b.w, w[4*q+3].x, xB0); xB1 = fmaf(b.w, w[4*q+3].y, xB1);
    }
    xA0 = gelu_f(xA0); xA1 = gelu_f(xA1);
    xB0 = gelu_f(xB0); xB1 = gelu_f(xB1);

    const float sumA = wave_sum(xA0 + xA1);
    const float sqA  = wave_sum(xA0 * xA0 + xA1 * xA1);
    const float sumB = wave_sum(xB0 + xB1);
    const float sqB  = wave_sum(xB0 * xB0 + xB1 * xB1);

    const float muA = sumA * (1.0f / 128.0f);
    const float invA = rsqrtf(sqA * (1.0f / 128.0f) - muA * muA + LN_EPS);
    const float muB = sumB * (1.0f / 128.0f);
    const float invB = rsqrtf(sqB * (1.0f / 128.0f) - muB * muB + LN_EPS);

    vfloat2 oA;
    oA.x = (xA0 - muA) * invA * gg.x + ee.x;
    oA.y = (xA1 - muA) * invA * gg.y + ee.y;
    __builtin_nontemporal_store(oA,
        reinterpret_cast<vfloat2*>(out + (size_t)r * 128 + 2 * lane));
    if (two) {
        vfloat2 oB;
        oB.x = (xB0 - muB) * invB * gg.x + ee.x;
        oB.y = (xB1 - muB) * invB * gg.y + ee.y;
        __builtin_nontemporal_store(oB,
            reinterpret_cast<vfloat2*>(out + (size_t)(r + 1) * 128 + 2 * lane));
    }
}

// Wave-specialized fusion: per 256-thread block, waves 0-1 compute 32 rows
// (LDS-staged, stall-free after one staged HBM latency); waves 2-3 handle 512
// edges (pure-memory chain: idx NT load issued FIRST -> L2 gathers -> NT
// stores). Det waves' stalls are hidden by row waves' VALU on the same SIMDs.
// At B=2,N=50000,E=1.6M: blocks_h == blocks_d == 3125, zero tail.
__global__ __launch_bounds__(256) void fused5_kernel(
    const float* __restrict__ stat, const float* __restrict__ fc_w,
    const float* __restrict__ fc_b, const float* __restrict__ ln_g,
    const float* __restrict__ ln_b, float* __restrict__ out,
    const float4* __restrict__ xyp, const int* __restrict__ ei,
    float* __restrict__ det, int n_rows, int E, int E_vec)
{
    __shared__ float srows[RPB * 16];   // 2 KB

    const int tidL = (int)threadIdx.x;
    const int lane = tidL & 63;
    const int wave = tidL >> 6;                 // 0..3
    const int R0   = blockIdx.x * RPB;
    const bool is_row = (wave < 2);

    // det stage 0: index loads as the first VMEM ops (HBM ~900cyc; hidden
    // under stage + barrier + row ramp-up)
    const int j  = (wave - 2) * 64 + lane;            // det-lane id 0..127
    const int i4 = (blockIdx.x * 128 + j) * 4;
    const bool has_det = (!is_row) && (i4 >= 0) && (i4 + 3 < E_vec);
    vint4 s = {0, 0, 0, 0}, d = {0, 0, 0, 0};
    if (has_det) {
        s = __builtin_nontemporal_load(reinterpret_cast<const vint4*>(ei + i4));
        d = __builtin_nontemporal_load(reinterpret_cast<const vint4*>(ei + E + i4));
    }

    // stage: 256 threads x 8 B = 2 KB, fully coalesced (clamped at tail)
    {
        int rq = R0 + (tidL >> 3);
        rq = rq < n_rows ? rq : (n_rows - 1);
        float2 v = *reinterpret_cast<const float2*>(
            stat + (size_t)rq * 16 + (tidL & 7) * 2);
        *reinterpret_cast<float2*>(&srows[tidL * 2]) = v;
    }

    vfloat2 w[16], bb, gg, ee;
    if (is_row) {
#pragma unroll
        for (int c = 0; c < 16; ++c)
            w[c] = *reinterpret_cast<const vfloat2*>(fc_w + c * 128 + 2 * lane);
        bb = *reinterpret_cast<const vfloat2*>(fc_b + 2 * lane);
        gg = *reinterpret_cast<const vfloat2*>(ln_g + 2 * lane);
        ee = *reinterpret_cast<const vfloat2*>(ln_b + 2 * lane);
    }

    __syncthreads();

    if (is_row) {
        const int r0 = R0 + wave * 16;
        const float* sbase = &srows[wave * 16 * 16];
        compute_pair_lds(out, sbase + 0*16,  r0 + 0,  n_rows, w, bb, gg, ee, lane);
        compute_pair_lds(out, sbase + 2*16,  r0 + 2,  n_rows, w, bb, gg, ee, lane);
        compute_pair_lds(out, sbase + 4*16,  r0 + 4,  n_rows, w, bb, gg, ee, lane);
        compute_pair_lds(out, sbase + 6*16,  r0 + 6,  n_rows, w, bb, gg, ee, lane);
        compute_pair_lds(out, sbase + 8*16,  r0 + 8,  n_rows, w, bb, gg, ee, lane);
        compute_pair_lds(out, sbase + 10*16, r0 + 10, n_rows, w, bb, gg, ee, lane);
        compute_pair_lds(out, sbase + 12*16, r0 + 12, n_rows, w, bb, gg, ee, lane);
        compute_pair_lds(out, sbase + 14*16, r0 + 14, n_rows, w, bb, gg, ee, lane);
    } else if (has_det) {
        // 8 independent L2 gathers (xyp is 800 KB, L2-resident, plain loads
        // to keep it cached), then consume + dwordx4 NT stores
        float4 gs0 = xyp[s.x], gd0 = xyp[d.x];
        float4 gs1 = xyp[s.y], gd1 = xyp[d.y];
        float4 gs2 = xyp[s.z], gd2 = xyp[d.z];
        float4 gs3 = xyp[s.w], gd3 = xyp[d.w];
        float dx, dy;
        vfloat4 o0, o1;
        dx = gs0.x - gd0.x; dy = gs0.y - gd0.y; o0.x = -0.5f * (dx*dx + dy*dy);
        dx = gs1.x - gd1.x; dy = gs1.y - gd1.y; o0.y = -0.5f * (dx*dx + dy*dy);
        dx = gs2.x - gd2.x; dy = gs2.y - gd2.y; o0.z = -0.5f * (dx*dx + dy*dy);
        dx = gs3.x - gd3.x; dy = gs3.y - gd3.y; o0.w = -0.5f * (dx*dx + dy*dy);
        dx = gs0.z - gd0.z; dy = gs0.w - gd0.w; o1.x = -0.5f * (dx*dx + dy*dy);
        dx = gs1.z - gd1.z; dy = gs1.w - gd1.w; o1.y = -0.5f * (dx*dx + dy*dy);
        dx = gs2.z - gd2.z; dy = gs2.w - gd2.w; o1.z = -0.5f * (dx*dx + dy*dy);
        dx = gs3.z - gd3.z; dy = gs3.w - gd3.w; o1.w = -0.5f * (dx*dx + dy*dy);
        __builtin_nontemporal_store(o0, reinterpret_cast<vfloat4*>(det + i4));
        __builtin_nontemporal_store(o1, reinterpret_cast<vfloat4*>(det + E + i4));
    }
}

// det-only tail / ws-less fallback
__global__ __launch_bounds__(256) void det_kernel_direct(
    const float* __restrict__ stat, const int* __restrict__ ei,
    float* __restrict__ det, int E, int N, int i0)
{
    int i = i0 + (blockIdx.x * blockDim.x + threadIdx.x) * 2;
    if (i >= E) return;
    int2 s = *reinterpret_cast<const int2*>(ei + i);
    int2 d = *reinterpret_cast<const int2*>(ei + E + i);
#pragma unroll
    for (int b = 0; b < 2; ++b) {
        const float* base = stat + (size_t)b * N * 16;
        float2 ps0 = *reinterpret_cast<const float2*>(base + (size_t)s.x * 16);
        float2 pd0 = *reinterpret_cast<const float2*>(base + (size_t)d.x * 16);
        float2 ps1 = *reinterpret_cast<const float2*>(base + (size_t)s.y * 16);
        float2 pd1 = *reinterpret_cast<const float2*>(base + (size_t)d.y * 16);
        float dx0 = ps0.x - pd0.x, dy0 = ps0.y - pd0.y;
        float dx1 = ps1.x - pd1.x, dy1 = ps1.y - pd1.y;
        float2 v;
        v.x = -0.5f * (dx0 * dx0 + dy0 * dy0);
        v.y = -0.5f * (dx1 * dx1 + dy1 * dy1);
        *reinterpret_cast<float2*>(det + (size_t)b * E + i) = v;
    }
}

extern "C" void kernel_launch(void* const* d_in, const int* in_sizes, int n_in,
                              void* d_out, int out_size, void* d_ws, size_t ws_size,
                              hipStream_t stream) {
    const float* stat = (const float*)d_in[0];
    const int*   ei   = (const int*)d_in[1];
    const float* fc_w = (const float*)d_in[2];
    const float* fc_b = (const float*)d_in[3];
    const float* ln_g = (const float*)d_in[4];
    const float* ln_b = (const float*)d_in[5];
    float* out = (float*)d_out;

    const int n_rows = in_sizes[0] / 16;   // B*N = 100000
    const int E      = in_sizes[1] / 2;    // 1600000
    const int N      = n_rows / 2;         // B = 2

    float* H0  = out;
    float* det = out + (size_t)n_rows * 128;
    float* xyp = (float*)d_ws;
    const bool use_ws = (ws_size >= (size_t)N * 4 * sizeof(float));

    if (use_ws) {
        pack_kernel<<<(N + 255) / 256, 256, 0, stream>>>(stat, (float4*)xyp, N);
        // fused det path needs 16B alignment of ei+E / det+E: requires E%4==0
        const int E_vec = (E % 4 == 0) ? E : 0;
        const int blocks_h = (n_rows + RPB - 1) / RPB;
        const int blocks_d = (E_vec + EPB - 1) / EPB;
        const int G = blocks_h > blocks_d ? blocks_h : blocks_d;
        fused5_kernel<<<G, 256, 0, stream>>>(stat, fc_w, fc_b, ln_g, ln_b, H0,
                                             (const float4*)xyp, ei, det,
                                             n_rows, E, E_vec);
        long long covered = (long long)G * EPB;
        if (covered > E_vec) covered = E_vec;
        if (covered < E) {
            const int rem_pairs = (int)((E - covered + 1) / 2);
            det_kernel_direct<<<(rem_pairs + 255) / 256, 256, 0, stream>>>(
                stat, ei, det, E, N, (int)covered);
        }
    } else {
        const int pairs = (E + 1) / 2;
        det_kernel_direct<<<(pairs + 255) / 256, 256, 0, stream>>>(stat, ei, det, E, N, 0);
        const int blocks_h = (n_rows + RPB - 1) / RPB;
        fused5_kernel<<<blocks_h, 256, 0, stream>>>(stat, fc_w, fc_b, ln_g, ln_b, H0,
                                                    (const float4*)xyp, ei, det,
                                                    n_rows, E, 0);
    }
}